// Round 1
// baseline (2492.823 us; speedup 1.0000x reference)
//
#include <hip/hip_runtime.h>
#include <math.h>

#define TT 150
#define BB 64
#define DD 2000
#define SS 3000
#define EE 100000
#define RESC 16
#define NSLOT 9     // rescales consumed at k=16,32,...,144
#define MSUB 32     // sub-max slots to spread atomicMax contention

struct __align__(16) ArcT { int from_off; int pdf_off; float ew; int pad; };

// ---- transpose+exp one frame [B][D] -> [D][B], 64-wide d tiles ----
__device__ inline void transpose_tile(const float* __restrict__ frame,
                                      float* __restrict__ dst,
                                      int tile, int tid, float* smem)
{
    int d0 = tile * 64;
    #pragma unroll
    for (int it = 0; it < 16; ++it) {
        int idx = it * 256 + tid;
        int dl = idx & 63, bl = idx >> 6;
        int d = d0 + dl;
        float v = 0.f;
        if (d < DD) v = __expf(frame[bl * DD + d]);   // coalesced in d
        smem[dl * 65 + bl] = v;                        // 2-way bank alias: free
    }
    __syncthreads();
    #pragma unroll
    for (int it = 0; it < 16; ++it) {
        int idx = it * 256 + tid;
        int bo = idx & 63, dq = idx >> 6;
        int d = d0 + dq;
        if (d < DD) dst[d * 64 + bo] = smem[dq * 65 + bo];  // coalesced in b
    }
}

__global__ void k_init(const float* __restrict__ init_logp,
                       float* __restrict__ A0, int* __restrict__ counts,
                       float* __restrict__ M2)
{
    int idx = blockIdx.x * blockDim.x + threadIdx.x;
    if (idx < SS * BB) A0[idx] = __expf(init_logp[idx >> 6]);
    if (idx < SS) counts[idx] = 0;
    if (idx < NSLOT * MSUB * 64) M2[idx] = 0.f;
}

__global__ void k_transpose(const float* __restrict__ frame, float* __restrict__ dst)
{
    __shared__ float smem[64 * 65];
    transpose_tile(frame, dst, blockIdx.x, threadIdx.x, smem);
}

__global__ void k_hist(const int* __restrict__ to_state, int* __restrict__ counts)
{
    int e = blockIdx.x * blockDim.x + threadIdx.x;
    if (e < EE) atomicAdd(&counts[e < EE ? to_state[e] : 0], 1);
}

__global__ void k_scan(const int* __restrict__ counts, int* __restrict__ rp,
                       int* __restrict__ cur)
{
    __shared__ int ls[1024];
    int tid = threadIdx.x;
    int s0 = tid * 3;
    int a0 = (s0 + 0 < SS) ? counts[s0 + 0] : 0;
    int a1 = (s0 + 1 < SS) ? counts[s0 + 1] : 0;
    int a2 = (s0 + 2 < SS) ? counts[s0 + 2] : 0;
    int tsum = a0 + a1 + a2;
    ls[tid] = tsum;
    __syncthreads();
    for (int off = 1; off < 1024; off <<= 1) {
        int v = ls[tid];
        int add = (tid >= off) ? ls[tid - off] : 0;
        __syncthreads();
        ls[tid] = v + add;
        __syncthreads();
    }
    int excl = ls[tid] - tsum;
    if (s0 + 0 < SS) { rp[s0 + 0] = excl; cur[s0 + 0] = excl; }
    excl += a0;
    if (s0 + 1 < SS) { rp[s0 + 1] = excl; cur[s0 + 1] = excl; }
    excl += a1;
    if (s0 + 2 < SS) { rp[s0 + 2] = excl; cur[s0 + 2] = excl; }
    if (tid == 1023) rp[SS] = ls[1023];
}

__global__ void k_scatter(const int* __restrict__ from_state, const int* __restrict__ to_state,
                          const int* __restrict__ pdf_id, const float* __restrict__ trans_logw,
                          int* __restrict__ cur, ArcT* __restrict__ arcs)
{
    int e = blockIdx.x * blockDim.x + threadIdx.x;
    if (e >= EE) return;
    int s = to_state[e];
    int pos = atomicAdd(&cur[s], 1);
    ArcT a;
    a.from_off = from_state[e] << 6;
    a.pdf_off  = pdf_id[e] << 6;
    a.ew = __expf(trans_logw[e]);
    a.pad = 0;
    arcs[pos] = a;
}

// One block (4 waves) per state; lane = batch idx. Blocks >= SS transpose next frame.
__global__ void __launch_bounds__(256) k_arc(
    const ArcT* __restrict__ arcs, const int* __restrict__ rp,
    const float* __restrict__ Aprev, float* __restrict__ Anext,
    const float* __restrict__ exCur,
    const float* __restrict__ frameNext, float* __restrict__ exNext,
    float* __restrict__ M2, int maxSlot, int useSlot)
{
    __shared__ float smem[64 * 65];   // transpose tile; arc blocks alias first 320 floats
    int tid = threadIdx.x;
    int bid = blockIdx.x;
    if (bid >= SS) { transpose_tile(frameNext, exNext, bid - SS, tid, smem); return; }

    int lane = tid & 63, wave = tid >> 6;
    float* part = smem;         // [4][64]
    float* rcpA = smem + 256;   // [64]
    if (useSlot >= 0 && wave == 0) {
        const float* Mrow = M2 + useSlot * (MSUB * 64);
        float m = Mrow[lane];
        #pragma unroll
        for (int g = 1; g < MSUB; ++g) m = fmaxf(m, Mrow[g * 64 + lane]);
        rcpA[lane] = 1.0f / m;
    }
    int rbeg = rp[bid], rend = rp[bid + 1];
    float acc = 0.f;
    for (int i = rbeg + wave; i < rend; i += 4) {
        ArcT a = arcs[i];                        // broadcast 16B
        float av = Aprev[a.from_off + lane];     // coalesced 256B row
        float ev = exCur[a.pdf_off + lane];      // coalesced 256B row
        acc = fmaf(av, a.ew * ev, acc);
    }
    part[tid] = acc;
    __syncthreads();
    if (wave == 0) {
        float sum = part[lane] + part[64 + lane] + part[128 + lane] + part[192 + lane];
        if (useSlot >= 0) sum *= rcpA[lane];
        Anext[(bid << 6) + lane] = sum;
        if (maxSlot >= 0)
            atomicMax((unsigned int*)&M2[maxSlot * (MSUB * 64) + (bid & (MSUB - 1)) * 64 + lane],
                      __float_as_uint(sum));     // sum >= 0, uint-monotone
    }
}

__global__ void k_final(const float* __restrict__ AT, const float* __restrict__ final_logp,
                        const float* __restrict__ M2, float* __restrict__ out)
{
    __shared__ float red[1024];
    int tid = threadIdx.x;
    int lane = tid & 63, chunk = tid >> 6;   // 16 s-chunks
    float psum = 0.f;
    for (int s = chunk; s < SS; s += 16)
        psum += AT[(s << 6) + lane] * __expf(final_logp[s]);
    red[tid] = psum;
    __syncthreads();
    if (tid < 64) {
        float ssum = 0.f;
        #pragma unroll
        for (int c = 0; c < 16; ++c) ssum += red[c * 64 + tid];
        float lg = logf(ssum);
        #pragma unroll
        for (int r = 0; r < NSLOT; ++r) {
            const float* Mrow = M2 + r * (MSUB * 64);
            float m = Mrow[tid];
            #pragma unroll
            for (int g = 1; g < MSUB; ++g) m = fmaxf(m, Mrow[g * 64 + tid]);
            lg += logf(m);   // identical max computation as the consumer -> exact compensation
        }
        #pragma unroll
        for (int off = 32; off > 0; off >>= 1) lg += __shfl_down(lg, off);
        if (tid == 0) out[0] = lg;
    }
}

extern "C" void kernel_launch(void* const* d_in, const int* in_sizes, int n_in,
                              void* d_out, int out_size, void* d_ws, size_t ws_size,
                              hipStream_t stream)
{
    const float* input      = (const float*)d_in[0];
    const float* trans_logw = (const float*)d_in[1];
    const float* init_logp  = (const float*)d_in[2];
    const float* final_logp = (const float*)d_in[3];
    const int*   from_state = (const int*)d_in[4];
    const int*   to_state   = (const int*)d_in[5];
    const int*   pdf_id     = (const int*)d_in[6];
    float* out = (float*)d_out;

    char* ws = (char*)d_ws;
    size_t off = 0;
    auto alloc = [&](size_t bytes) -> char* {
        char* p = ws + off;
        off = (off + bytes + 255) & ~(size_t)255;
        return p;
    };
    float* ex0   = (float*)alloc((size_t)DD * BB * 4);
    float* ex1   = (float*)alloc((size_t)DD * BB * 4);
    float* A0    = (float*)alloc((size_t)SS * BB * 4);
    float* A1    = (float*)alloc((size_t)SS * BB * 4);
    ArcT* arcs   = (ArcT*)alloc((size_t)EE * 16);
    int* rp      = (int*)alloc((size_t)(SS + 1) * 4);
    int* cur     = (int*)alloc((size_t)SS * 4);
    int* counts  = (int*)alloc((size_t)SS * 4);
    float* M2    = (float*)alloc((size_t)NSLOT * MSUB * 64 * 4);
    (void)ws_size; (void)in_sizes; (void)n_in; (void)out_size;

    k_init<<<(SS * BB + 255) / 256, 256, 0, stream>>>(init_logp, A0, counts, M2);
    k_hist<<<(EE + 255) / 256, 256, 0, stream>>>(to_state, counts);
    k_scan<<<1, 1024, 0, stream>>>(counts, rp, cur);
    k_scatter<<<(EE + 255) / 256, 256, 0, stream>>>(from_state, to_state, pdf_id,
                                                    trans_logw, cur, arcs);
    k_transpose<<<32, 256, 0, stream>>>(input, ex0);

    float* A[2]  = {A0, A1};
    float* ex[2] = {ex0, ex1};
    for (int k = 0; k < TT; ++k) {
        int kn = k + 1;
        int useSlot = (k > 0 && (k % RESC) == 0) ? (k / RESC - 1) : -1;
        int maxSlot = (kn < TT && (kn % RESC) == 0) ? (kn / RESC - 1) : -1;
        int grid = SS + ((kn < TT) ? 32 : 0);
        const float* fnext = (kn < TT) ? (input + (size_t)kn * BB * DD) : nullptr;
        k_arc<<<grid, 256, 0, stream>>>(arcs, rp, A[k & 1], A[kn & 1], ex[k & 1],
                                        fnext, ex[kn & 1], M2, maxSlot, useSlot);
    }
    k_final<<<1, 1024, 0, stream>>>(A[TT & 1], final_logp, M2, out);
}

// Round 3
// 2319.262 us; speedup vs baseline: 1.0748x; 1.0748x over previous
//
#include <hip/hip_runtime.h>
#include <hip/hip_cooperative_groups.h>
#include <math.h>

namespace cg = cooperative_groups;

#define TT 150
#define BB 64
#define DD 2000
#define SS 3000
#define EE 100000
#define RESC 16
#define NSLOT 9      // rescales consumed at k=16,32,...,144
#define MSUB 16      // sub-max slots to spread atomicMax contention
#define NPART 16     // partial-sum slots for final reduce

#define NT 1024      // coop: threads per block (16 waves)
#define NWAVE 16
#define NBLK 256     // coop: 1 block per CU -> co-residency guaranteed
#define NARCB 224    // arc blocks: 224*16 = 3584 wave slots >= SS
#define NEXB 32      // ex-transpose blocks (32 tiles of 64 d-columns)
#define MAXARC 128   // per-state LDS arc capacity (mean 33.3, max ~56)

struct __align__(8) ArcT2 { unsigned idx; float ew; };   // idx = from | (pdf<<16)

__device__ inline float b2f(unsigned short u) {
    union { unsigned u32; float f; } x; x.u32 = ((unsigned)u) << 16; return x.f;
}
__device__ inline unsigned short f2b(float f) {
    union { float f; unsigned u; } x; x.f = f;
    unsigned r = x.u + 0x7FFF + ((x.u >> 16) & 1);       // RNE, positive finite only
    return (unsigned short)(r >> 16);
}

// transpose+exp one 64(d)x64(b) tile of frame [B][D] -> bf16 [D][64]
template <int THREADS>
__device__ inline void transpose_exp_t(const float* __restrict__ frame,
                                       unsigned short* __restrict__ dst,
                                       int tile_id, int tid, unsigned short* smem)
{
    int d0 = tile_id * 64;
    #pragma unroll
    for (int it = 0; it < 4096 / THREADS; ++it) {
        int idx = it * THREADS + tid;
        int dl = idx & 63, bl = idx >> 6;
        int d = d0 + dl;
        float v = 0.f;
        if (d < DD) v = __expf(frame[bl * DD + d]);      // coalesced in d
        smem[dl * 65 + bl] = f2b(v);
    }
    __syncthreads();
    #pragma unroll
    for (int it = 0; it < 4096 / THREADS; ++it) {
        int idx = it * THREADS + tid;
        int bo = idx & 63, dq = idx >> 6;
        int d = d0 + dq;
        if (d < DD) dst[(d << 6) + bo] = smem[dq * 65 + bo];  // coalesced in b
    }
    __syncthreads();
}

// ---------------- setup kernels (CSR build) ----------------
__global__ void k_init(int* __restrict__ counts)
{
    int i = blockIdx.x * blockDim.x + threadIdx.x;
    if (i < SS) counts[i] = 0;
}

__global__ void k_hist(const int* __restrict__ to_state, int* __restrict__ counts)
{
    int e = blockIdx.x * blockDim.x + threadIdx.x;
    if (e < EE) atomicAdd(&counts[to_state[e]], 1);
}

__global__ void k_scan(const int* __restrict__ counts, int* __restrict__ rp,
                       int* __restrict__ cur)
{
    __shared__ int ls[1024];
    int tid = threadIdx.x;
    int s0 = tid * 3;
    int a0 = (s0 + 0 < SS) ? counts[s0 + 0] : 0;
    int a1 = (s0 + 1 < SS) ? counts[s0 + 1] : 0;
    int a2 = (s0 + 2 < SS) ? counts[s0 + 2] : 0;
    int tsum = a0 + a1 + a2;
    ls[tid] = tsum;
    __syncthreads();
    for (int off = 1; off < 1024; off <<= 1) {
        int v = ls[tid];
        int add = (tid >= off) ? ls[tid - off] : 0;
        __syncthreads();
        ls[tid] = v + add;
        __syncthreads();
    }
    int excl = ls[tid] - tsum;
    if (s0 + 0 < SS) { rp[s0 + 0] = excl; cur[s0 + 0] = excl; }
    excl += a0;
    if (s0 + 1 < SS) { rp[s0 + 1] = excl; cur[s0 + 1] = excl; }
    excl += a1;
    if (s0 + 2 < SS) { rp[s0 + 2] = excl; cur[s0 + 2] = excl; }
    if (tid == 1023) rp[SS] = ls[1023];
}

__global__ void k_scatter(const int* __restrict__ from_state, const int* __restrict__ to_state,
                          const int* __restrict__ pdf_id, const float* __restrict__ trans_logw,
                          int* __restrict__ cur, ArcT2* __restrict__ arcs)
{
    int e = blockIdx.x * blockDim.x + threadIdx.x;
    if (e >= EE) return;
    int s = to_state[e];
    int pos = atomicAdd(&cur[s], 1);
    ArcT2 a;
    a.idx = (unsigned)from_state[e] | ((unsigned)pdf_id[e] << 16);
    a.ew = __expf(trans_logw[e]);
    arcs[pos] = a;
}

// ---------------- cooperative mega-kernel (primary path) ----------------
__global__ void __launch_bounds__(NT, 4) k_coop(
    const ArcT2* __restrict__ arcs, const int* __restrict__ rp,
    const float* __restrict__ input, const float* __restrict__ init_logp,
    const float* __restrict__ final_logp,
    float* __restrict__ M2,            // [NSLOT][MSUB][64]
    float* __restrict__ partial,       // [NPART][64]
    unsigned short* __restrict__ A0, unsigned short* __restrict__ A1,
    unsigned short* __restrict__ EX0, unsigned short* __restrict__ EX1,
    float* __restrict__ out)
{
    cg::grid_group grid = cg::this_grid();
    __shared__ unsigned short tile[64 * 65];         // 8.3 KB (ex blocks)
    __shared__ ArcT2 larc[NWAVE * MAXARC];           // 16 KB  (arc blocks)
    __shared__ float red[NT];                        // 4 KB   (epilogue)

    int tid = threadIdx.x, bid = blockIdx.x;
    int lane = tid & 63, wave = tid >> 6;
    bool isArc = (bid < NARCB);

    // ---- prologue: alpha0, zero M2/partial, stage arcs to LDS, ex frame 0 ----
    for (int idx = bid * NT + tid; idx < SS * BB; idx += NBLK * NT)
        A0[idx] = f2b(__expf(init_logp[idx >> 6]));
    for (int idx = bid * NT + tid; idx < NSLOT * MSUB * 64 + NPART * 64; idx += NBLK * NT) {
        if (idx < NSLOT * MSUB * 64) M2[idx] = 0.f;
        else partial[idx - NSLOT * MSUB * 64] = 0.f;
    }
    int s = -1, rbeg = 0, rend = 0, nloc = 0;
    if (isArc) {
        int cand = wave * NARCB + bid;               // interleaved for balance
        if (cand < SS) {
            s = cand; rbeg = rp[s]; rend = rp[s + 1];
            nloc = rend - rbeg; if (nloc > MAXARC) nloc = MAXARC;
            for (int i = lane; i < nloc; i += 64)
                larc[wave * MAXARC + i] = arcs[rbeg + i];   // resident all 150 steps
        }
    } else {
        transpose_exp_t<NT>(input, EX0, bid - NARCB, tid, tile);  // frame 0
    }
    grid.sync();

    // ---- 150 sequential steps, one grid.sync each ----
    for (int k = 0; k < TT; ++k) {
        const unsigned short* Ap = (k & 1) ? A1 : A0;
        unsigned short*       An = (k & 1) ? A0 : A1;
        const unsigned short* ec = (k & 1) ? EX1 : EX0;
        unsigned short*       en = (k & 1) ? EX0 : EX1;
        if (isArc) {
            if (s >= 0) {
                float rcp = 1.f;
                if (k > 0 && (k % RESC) == 0) {
                    int slot = k / RESC - 1;
                    const float* Mrow = M2 + slot * (MSUB * 64);
                    float m = Mrow[lane];
                    #pragma unroll
                    for (int g = 1; g < MSUB; ++g) m = fmaxf(m, Mrow[g * 64 + lane]);
                    rcp = 1.0f / m;
                }
                float acc = 0.f;
                #pragma unroll 4
                for (int i = 0; i < nloc; ++i) {
                    ArcT2 a = larc[wave * MAXARC + i];       // LDS broadcast
                    int from = a.idx & 0xFFFF, pdf = a.idx >> 16;
                    float av = b2f(Ap[(from << 6) + lane]);  // 128B coalesced row
                    float ev = b2f(ec[(pdf << 6) + lane]);
                    acc = fmaf(av, a.ew * ev, acc);
                }
                for (int i = rbeg + nloc; i < rend; ++i) {   // overflow (not expected)
                    ArcT2 a = arcs[i];
                    int from = a.idx & 0xFFFF, pdf = a.idx >> 16;
                    acc = fmaf(b2f(Ap[(from << 6) + lane]), a.ew * b2f(ec[(pdf << 6) + lane]), acc);
                }
                acc *= rcp;
                An[(s << 6) + lane] = f2b(acc);
                int kn = k + 1;
                if (kn < TT && (kn % RESC) == 0) {
                    int slot = kn / RESC - 1;
                    atomicMax((unsigned*)&M2[slot * (MSUB * 64) + (s & (MSUB - 1)) * 64 + lane],
                              __float_as_uint(acc));         // acc >= 0: uint-monotone
                }
            }
        } else if (k + 1 < TT) {
            transpose_exp_t<NT>(input + (size_t)(k + 1) * BB * DD, en, bid - NARCB, tid, tile);
        }
        grid.sync();
    }

    // ---- epilogue: objf = sum_b [ log(sum_s aT*e^f) + sum_r log(m_r[b]) ] ----
    float v = 0.f;
    if (isArc && s >= 0)
        v = b2f(A0[(s << 6) + lane]) * __expf(final_logp[s]);   // TT even -> alpha_T in A0
    red[tid] = v;
    __syncthreads();
    if (wave == 0 && isArc) {
        float t = 0.f;
        #pragma unroll
        for (int w = 0; w < NWAVE; ++w) t += red[w * 64 + lane];
        atomicAdd(&partial[(bid & (NPART - 1)) * 64 + lane], t);
    }
    grid.sync();
    if (bid == 0 && tid < 64) {
        float sum = 0.f;
        #pragma unroll
        for (int c = 0; c < NPART; ++c) sum += partial[c * 64 + tid];
        float lg = logf(sum);
        #pragma unroll
        for (int r = 0; r < NSLOT; ++r) {
            const float* Mrow = M2 + r * (MSUB * 64);
            float m = Mrow[tid];
            #pragma unroll
            for (int g = 1; g < MSUB; ++g) m = fmaxf(m, Mrow[g * 64 + tid]);
            lg += logf(m);   // same max computation as consumer -> exact compensation
        }
        #pragma unroll
        for (int off = 32; off > 0; off >>= 1) lg += __shfl_down(lg, off);
        if (tid == 0) out[0] = lg;
    }
}

// ---------------- fallback path (per-step kernels, round-1 structure) ----------------
__global__ void k_initA(const float* __restrict__ init_logp,
                        unsigned short* __restrict__ A0, float* __restrict__ M2)
{
    int idx = blockIdx.x * blockDim.x + threadIdx.x;
    if (idx < SS * BB) A0[idx] = f2b(__expf(init_logp[idx >> 6]));
    if (idx < NSLOT * MSUB * 64) M2[idx] = 0.f;
}

__global__ void k_transpose0(const float* __restrict__ frame, unsigned short* __restrict__ dst)
{
    __shared__ unsigned short tile[64 * 65];
    transpose_exp_t<256>(frame, dst, blockIdx.x, threadIdx.x, tile);
}

__global__ void __launch_bounds__(256) k_step(
    const ArcT2* __restrict__ arcs, const int* __restrict__ rp,
    const unsigned short* __restrict__ Ap, unsigned short* __restrict__ An,
    const unsigned short* __restrict__ ec,
    const float* __restrict__ frameNext, unsigned short* __restrict__ en,
    float* __restrict__ M2, int maxSlot, int useSlot)
{
    __shared__ unsigned short tile[64 * 65];
    __shared__ float part[256];
    __shared__ float rcpA[64];
    int tid = threadIdx.x, bid = blockIdx.x;
    if (bid >= SS) { transpose_exp_t<256>(frameNext, en, bid - SS, tid, tile); return; }
    int lane = tid & 63, wave = tid >> 6;
    if (useSlot >= 0 && wave == 0) {
        const float* Mrow = M2 + useSlot * (MSUB * 64);
        float m = Mrow[lane];
        #pragma unroll
        for (int g = 1; g < MSUB; ++g) m = fmaxf(m, Mrow[g * 64 + lane]);
        rcpA[lane] = 1.0f / m;
    }
    int rbeg = rp[bid], rend = rp[bid + 1];
    float acc = 0.f;
    for (int i = rbeg + wave; i < rend; i += 4) {
        ArcT2 a = arcs[i];
        int from = a.idx & 0xFFFF, pdf = a.idx >> 16;
        acc = fmaf(b2f(Ap[(from << 6) + lane]), a.ew * b2f(ec[(pdf << 6) + lane]), acc);
    }
    part[tid] = acc;
    __syncthreads();
    if (wave == 0) {
        float sum = part[lane] + part[64 + lane] + part[128 + lane] + part[192 + lane];
        if (useSlot >= 0) sum *= rcpA[lane];
        An[(bid << 6) + lane] = f2b(sum);
        if (maxSlot >= 0)
            atomicMax((unsigned*)&M2[maxSlot * (MSUB * 64) + (bid & (MSUB - 1)) * 64 + lane],
                      __float_as_uint(sum));
    }
}

__global__ void k_fin(const unsigned short* __restrict__ AT, const float* __restrict__ final_logp,
                      const float* __restrict__ M2, float* __restrict__ out)
{
    __shared__ float red[1024];
    int tid = threadIdx.x;
    int lane = tid & 63, chunk = tid >> 6;
    float psum = 0.f;
    for (int s = chunk; s < SS; s += 16)
        psum += b2f(AT[(s << 6) + lane]) * __expf(final_logp[s]);
    red[tid] = psum;
    __syncthreads();
    if (tid < 64) {
        float sum = 0.f;
        #pragma unroll
        for (int c = 0; c < 16; ++c) sum += red[c * 64 + tid];
        float lg = logf(sum);
        #pragma unroll
        for (int r = 0; r < NSLOT; ++r) {
            const float* Mrow = M2 + r * (MSUB * 64);
            float m = Mrow[tid];
            #pragma unroll
            for (int g = 1; g < MSUB; ++g) m = fmaxf(m, Mrow[g * 64 + tid]);
            lg += logf(m);
        }
        #pragma unroll
        for (int off = 32; off > 0; off >>= 1) lg += __shfl_down(lg, off);
        if (tid == 0) out[0] = lg;
    }
}

extern "C" void kernel_launch(void* const* d_in, const int* in_sizes, int n_in,
                              void* d_out, int out_size, void* d_ws, size_t ws_size,
                              hipStream_t stream)
{
    const float* input      = (const float*)d_in[0];
    const float* trans_logw = (const float*)d_in[1];
    const float* init_logp  = (const float*)d_in[2];
    const float* final_logp = (const float*)d_in[3];
    const int*   from_state = (const int*)d_in[4];
    const int*   to_state   = (const int*)d_in[5];
    const int*   pdf_id     = (const int*)d_in[6];
    float* out = (float*)d_out;

    char* ws = (char*)d_ws;
    size_t off = 0;
    auto alloc = [&](size_t bytes) -> char* {
        char* p = ws + off;
        off = (off + bytes + 255) & ~(size_t)255;
        return p;
    };
    ArcT2* arcs  = (ArcT2*)alloc((size_t)EE * sizeof(ArcT2));
    int* rp      = (int*)alloc((size_t)(SS + 1) * 4);
    int* cur     = (int*)alloc((size_t)SS * 4);
    int* counts  = (int*)alloc((size_t)SS * 4);
    unsigned short* A0  = (unsigned short*)alloc((size_t)SS * BB * 2);
    unsigned short* A1  = (unsigned short*)alloc((size_t)SS * BB * 2);
    unsigned short* EX0 = (unsigned short*)alloc((size_t)DD * BB * 2);
    unsigned short* EX1 = (unsigned short*)alloc((size_t)DD * BB * 2);
    float* M2    = (float*)alloc((size_t)NSLOT * MSUB * 64 * 4);
    float* partial = (float*)alloc((size_t)NPART * 64 * 4);
    (void)ws_size; (void)in_sizes; (void)n_in; (void)out_size;

    k_init<<<(SS + 255) / 256, 256, 0, stream>>>(counts);
    k_hist<<<(EE + 255) / 256, 256, 0, stream>>>(to_state, counts);
    k_scan<<<1, 1024, 0, stream>>>(counts, rp, cur);
    k_scatter<<<(EE + 255) / 256, 256, 0, stream>>>(from_state, to_state, pdf_id,
                                                    trans_logw, cur, arcs);

    // Decide path with a capture-safe host query (deterministic across calls).
    int nb = 0;
    hipOccupancyMaxActiveBlocksPerMultiprocessor(&nb, (const void*)k_coop, NT, 0);
    if (nb >= 1) {
        void* kp[12] = {
            (void*)&arcs, (void*)&rp, (void*)&input, (void*)&init_logp, (void*)&final_logp,
            (void*)&M2, (void*)&partial, (void*)&A0, (void*)&A1, (void*)&EX0, (void*)&EX1,
            (void*)&out
        };
        hipError_t e = hipLaunchCooperativeKernel((const void*)k_coop, dim3(NBLK), dim3(NT),
                                                  kp, 0, stream);
        if (e == hipSuccess) return;
    }

    // Fallback: per-step kernels (round-1 structure, bf16 state).
    k_initA<<<(SS * BB + 255) / 256, 256, 0, stream>>>(init_logp, A0, M2);
    k_transpose0<<<NEXB, 256, 0, stream>>>(input, EX0);
    unsigned short* A[2]  = {A0, A1};
    unsigned short* EX[2] = {EX0, EX1};
    for (int k = 0; k < TT; ++k) {
        int kn = k + 1;
        int useSlot = (k > 0 && (k % RESC) == 0) ? (k / RESC - 1) : -1;
        int maxSlot = (kn < TT && (kn % RESC) == 0) ? (kn / RESC - 1) : -1;
        int grid = SS + ((kn < TT) ? NEXB : 0);
        const float* fnext = (kn < TT) ? (input + (size_t)kn * BB * DD) : nullptr;
        k_step<<<grid, 256, 0, stream>>>(arcs, rp, A[k & 1], A[kn & 1], EX[k & 1],
                                         fnext, EX[kn & 1], M2, maxSlot, useSlot);
    }
    k_fin<<<1, 1024, 0, stream>>>(A[TT & 1], final_logp, M2, out);
}